// Round 9
// baseline (344.755 us; speedup 1.0000x reference)
//
#include <hip/hip_runtime.h>

#define B_  128
#define LC_ 512
#define LM_ 512
#define D_  512

typedef __attribute__((ext_vector_type(8))) short short8;
typedef __attribute__((ext_vector_type(16))) float f32x16;
typedef unsigned int u32;

__device__ __forceinline__ unsigned short bf16_rn(float x) {
  unsigned u = __float_as_uint(x);
  unsigned r = u + 0x7fffu + ((u >> 16) & 1u);
  return (unsigned short)(r >> 16);
}

__device__ __forceinline__ void gl_lds16(const void* g, void* l) {
  __builtin_amdgcn_global_load_lds((const __attribute__((address_space(1))) u32*)g,
                                   (__attribute__((address_space(3))) u32*)l, 16, 0, 0);
}

// one fp32 -> (hi,lo) bf16 split + u-dot accumulate; constant IDX only
#define CVT1(SRC, WS, AH, AL, IDX, ACCU)                         \
  { unsigned short hb_ = bf16_rn(SRC);                           \
    float hf_ = __uint_as_float((u32)hb_ << 16);                 \
    AH[IDX] = (short)hb_;                                        \
    AL[IDX] = (short)bf16_rn((SRC) - hf_);                       \
    ACCU = fmaf((SRC), (WS), ACCU); }

// ---------------- k_cvt_main: main fp32 -> tiled fragment-order bf16 planes
// Bt[b][ks][mt][lane][8]; also fused v = main·W. Wave = one (b, mt) tile.
__global__ __launch_bounds__(256) void k_cvt_main(
    const float* __restrict__ mn, const float* __restrict__ W,
    short* __restrict__ BtH, short* __restrict__ BtL,
    float* __restrict__ v) {
  __shared__ float sW[512];
  int tid = threadIdx.x;
  sW[tid] = W[tid];
  sW[tid + 256] = W[tid + 256];
  __syncthreads();
  int wave = blockIdx.x * 4 + (tid >> 6);
  int b = wave >> 4, mt = wave & 15;
  int lane = tid & 63, rowl = lane & 31, h = lane >> 5;
  const float* src = mn + ((size_t)b * LM_ + 32 * mt + rowl) * D_ + 8 * h;
  float acc = 0.f;
  for (int ks = 0; ks < 32; ks++) {
    float4 f0 = *(const float4*)(src + 16 * ks);
    float4 f1 = *(const float4*)(src + 16 * ks + 4);
    int k = 16 * ks + 8 * h;
    float4 w0 = *(const float4*)&sW[k];
    float4 w1 = *(const float4*)&sW[k + 4];
    short8 vh, vl;
    CVT1(f0.x, w0.x, vh, vl, 0, acc); CVT1(f0.y, w0.y, vh, vl, 1, acc);
    CVT1(f0.z, w0.z, vh, vl, 2, acc); CVT1(f0.w, w0.w, vh, vl, 3, acc);
    CVT1(f1.x, w1.x, vh, vl, 4, acc); CVT1(f1.y, w1.y, vh, vl, 5, acc);
    CVT1(f1.z, w1.z, vh, vl, 6, acc); CVT1(f1.w, w1.w, vh, vl, 7, acc);
    size_t off = (((size_t)b * 32 + ks) * 16 + mt) * 512 + (size_t)lane * 8;
    *(short8*)(BtH + off) = vh;
    *(short8*)(BtL + off) = vl;
  }
  acc += __shfl_xor(acc, 32, 64);
  if (h == 0) v[b * LM_ + 32 * mt + rowl] = acc;
}

// ---------------- k_scores_mfma5: 64c x 512m block, 4 waves, 2 blocks/CU ---
// B staged via gl_lds from tiled planes; A loaded + converted per-wave in
// registers each K-step (straight-line, no rotation, no setprio).
struct __align__(16) Smem4 {
  short8 Bf[2][2][16][64];   // [buf][plane][mt][lane]  64 KB
  float sW[512];             // 2 KB
  float red[4][64];          // 1 KB
  float cmb[64];
  float uld[64];
};

__global__ __launch_bounds__(256, 2) void k_scores_mfma5(
    const float* __restrict__ ctx, const short* __restrict__ BtH,
    const short* __restrict__ BtL, const float* __restrict__ W,
    float* __restrict__ P, float* __restrict__ tpart) {
  __shared__ Smem4 sm;
  int p = blockIdx.x;
  int b = (p & 7) | ((p >> 6) << 3);   // 8 c-blocks of a batch -> same XCD
  int cblk = (p >> 3) & 7;
  int c0 = cblk * 64;
  int tid = threadIdx.x;
  int lane = tid & 63, wv = tid >> 6;
  int rowl = lane & 31, h = lane >> 5;

  f32x16 acc0[4], acc1[4];             // row-tile 0 / 1, 128 AGPR total
  #pragma unroll
  for (int m = 0; m < 4; m++)
    #pragma unroll
    for (int j = 0; j < 16; j++) { acc0[m][j] = 0.f; acc1[m][j] = 0.f; }

  auto stageB = [&](int bf, int ks) {
    #pragma unroll
    for (int rep = 0; rep < 4; rep++) {
      int mt = wv + 4 * rep;
      size_t off = (((size_t)b * 32 + ks) * 16 + mt) * 512 + (size_t)lane * 8;
      gl_lds16(BtH + off, &sm.Bf[bf][0][mt][0]);
      gl_lds16(BtL + off, &sm.Bf[bf][1][mt][0]);
    }
  };

  const float* ar0 = ctx + ((size_t)b * LC_ + c0 +      rowl) * D_ + 8 * h;
  const float* ar1 = ctx + ((size_t)b * LC_ + c0 + 32 + rowl) * D_ + 8 * h;

  sm.sW[tid] = W[tid];
  sm.sW[tid + 256] = W[tid + 256];
  stageB(0, 0);
  float accu0 = 0.f, accu1 = 0.f;
  __syncthreads();                     // sW visible + Bf[0] drained

  for (int ks = 0; ks < 32; ks++) {
    int buf = ks & 1;
    if (ks < 31) stageB(buf ^ 1, ks + 1);

    int k = 16 * ks + 8 * h;
    float4 w0 = *(const float4*)&sm.sW[k];
    float4 w1 = *(const float4*)&sm.sW[k + 4];
    short8 ah0, al0, ah1, al1;
    {
      const float* p0 = ar0 + 16 * ks;
      float4 g0 = *(const float4*)p0;
      float4 g1 = *(const float4*)(p0 + 4);
      CVT1(g0.x, w0.x, ah0, al0, 0, accu0); CVT1(g0.y, w0.y, ah0, al0, 1, accu0);
      CVT1(g0.z, w0.z, ah0, al0, 2, accu0); CVT1(g0.w, w0.w, ah0, al0, 3, accu0);
      CVT1(g1.x, w1.x, ah0, al0, 4, accu0); CVT1(g1.y, w1.y, ah0, al0, 5, accu0);
      CVT1(g1.z, w1.z, ah0, al0, 6, accu0); CVT1(g1.w, w1.w, ah0, al0, 7, accu0);
    }
    {
      const float* p1 = ar1 + 16 * ks;
      float4 g0 = *(const float4*)p1;
      float4 g1 = *(const float4*)(p1 + 4);
      CVT1(g0.x, w0.x, ah1, al1, 0, accu1); CVT1(g0.y, w0.y, ah1, al1, 1, accu1);
      CVT1(g0.z, w0.z, ah1, al1, 2, accu1); CVT1(g0.w, w0.w, ah1, al1, 3, accu1);
      CVT1(g1.x, w1.x, ah1, al1, 4, accu1); CVT1(g1.y, w1.y, ah1, al1, 5, accu1);
      CVT1(g1.z, w1.z, ah1, al1, 6, accu1); CVT1(g1.w, w1.w, ah1, al1, 7, accu1);
    }

    #pragma unroll
    for (int mtl = 0; mtl < 4; mtl++) {
      int mt = 4 * wv + mtl;
      short8 bh = sm.Bf[buf][0][mt][lane];
      short8 bl = sm.Bf[buf][1][mt][lane];
      acc0[mtl] = __builtin_amdgcn_mfma_f32_32x32x16_bf16(ah0, bh, acc0[mtl], 0, 0, 0);
      acc0[mtl] = __builtin_amdgcn_mfma_f32_32x32x16_bf16(ah0, bl, acc0[mtl], 0, 0, 0);
      acc0[mtl] = __builtin_amdgcn_mfma_f32_32x32x16_bf16(al0, bh, acc0[mtl], 0, 0, 0);
      acc1[mtl] = __builtin_amdgcn_mfma_f32_32x32x16_bf16(ah1, bh, acc1[mtl], 0, 0, 0);
      acc1[mtl] = __builtin_amdgcn_mfma_f32_32x32x16_bf16(ah1, bl, acc1[mtl], 0, 0, 0);
      acc1[mtl] = __builtin_amdgcn_mfma_f32_32x32x16_bf16(al1, bh, acc1[mtl], 0, 0, 0);
    }
    __syncthreads();
  }

  // u for the block's 64 c-rows (all waves computed duplicates; wave 0 writes)
  accu0 += __shfl_xor(accu0, 32, 64);
  accu1 += __shfl_xor(accu1, 32, 64);
  if (wv == 0 && h == 0) {
    sm.uld[rowl] = accu0;
    sm.uld[32 + rowl] = accu1;
  }

  // ---- softmax over m=512 per c-row (cross-wave via LDS) ----
  #pragma unroll
  for (int r = 0; r < 2; r++)
    #pragma unroll
    for (int j = 0; j < 16; j++) {
      float a0 = r ? acc1[0][j] : acc0[0][j];
      float a1 = r ? acc1[1][j] : acc0[1][j];
      float a2 = r ? acc1[2][j] : acc0[2][j];
      float a3 = r ? acc1[3][j] : acc0[3][j];
      float mx = fmaxf(fmaxf(a0, a1), fmaxf(a2, a3));
      #pragma unroll
      for (int s = 1; s <= 16; s <<= 1) mx = fmaxf(mx, __shfl_xor(mx, s, 64));
      if (rowl == 0)
        sm.red[wv][32 * r + (j & 3) + 8 * (j >> 2) + 4 * h] = mx;
    }
  __syncthreads();
  if (tid < 64)
    sm.cmb[tid] = fmaxf(fmaxf(sm.red[0][tid], sm.red[1][tid]),
                        fmaxf(sm.red[2][tid], sm.red[3][tid]));
  __syncthreads();
  #pragma unroll
  for (int r = 0; r < 2; r++)
    #pragma unroll
    for (int j = 0; j < 16; j++) {
      int row = 32 * r + (j & 3) + 8 * (j >> 2) + 4 * h;
      float mx = sm.cmb[row];
      float s = 0.f;
      #pragma unroll
      for (int mtl = 0; mtl < 4; mtl++) {
        float e = __expf((r ? acc1[mtl][j] : acc0[mtl][j]) - mx);
        if (r) acc1[mtl][j] = e; else acc0[mtl][j] = e;
        s += e;
      }
      #pragma unroll
      for (int st = 1; st <= 16; st <<= 1) s += __shfl_xor(s, st, 64);
      if (rowl == 0) sm.red[wv][row] = s;
    }
  __syncthreads();
  if (tid < 64)
    sm.cmb[tid] = sm.red[0][tid] + sm.red[1][tid] + sm.red[2][tid] + sm.red[3][tid];
  __syncthreads();

  // ---- P write + fused t-partials (wave owns cols [128wv, 128wv+128)) ----
  float* Pb = P + ((size_t)b * LC_ + c0) * LM_;
  float tp[4] = {0.f, 0.f, 0.f, 0.f};
  #pragma unroll
  for (int r = 0; r < 2; r++)
    #pragma unroll
    for (int j = 0; j < 16; j++) {
      int row = 32 * r + (j & 3) + 8 * (j >> 2) + 4 * h;
      float rinv = 1.f / sm.cmb[row];
      float uu = sm.uld[row];
      #pragma unroll
      for (int mtl = 0; mtl < 4; mtl++) {
        float pv = (r ? acc1[mtl][j] : acc0[mtl][j]) * rinv;
        Pb[(size_t)row * LM_ + 128 * wv + 32 * mtl + rowl] = pv;
        tp[mtl] = fmaf(pv, uu, tp[mtl]);
      }
    }
  #pragma unroll
  for (int mtl = 0; mtl < 4; mtl++) tp[mtl] += __shfl_xor(tp[mtl], 32, 64);
  if (h == 0) {
    float* tpb = tpart + ((size_t)b * 8 + cblk) * LM_;
    #pragma unroll
    for (int mtl = 0; mtl < 4; mtl++)
      tpb[128 * wv + 32 * mtl + rowl] = tp[mtl];
  }
}

// ---------------- k_tw: t = v - sum(tpart, 8); w = softmax(t) --------------
__global__ __launch_bounds__(256) void k_tw(const float* __restrict__ tpart,
                                            const float* __restrict__ v,
                                            float* __restrict__ w_) {
  int b = blockIdx.x;
  int tid = threadIdx.x;
  int m0 = tid * 2;
  const float* tp = tpart + (size_t)b * 8 * LM_;
  float s0 = 0.f, s1 = 0.f;
  #pragma unroll
  for (int cb = 0; cb < 8; cb++) {
    s0 += tp[cb * LM_ + m0];
    s1 += tp[cb * LM_ + m0 + 1];
  }
  float x0 = v[b * LM_ + m0] - s0;
  float x1 = v[b * LM_ + m0 + 1] - s1;
  float mx = fmaxf(x0, x1);
  #pragma unroll
  for (int s = 32; s >= 1; s >>= 1) mx = fmaxf(mx, __shfl_xor(mx, s, 64));
  __shared__ float redm[4], reds[4];
  int wvv = tid >> 6, ln = tid & 63;
  if (ln == 0) redm[wvv] = mx;
  __syncthreads();
  mx = fmaxf(fmaxf(redm[0], redm[1]), fmaxf(redm[2], redm[3]));
  float e0 = __expf(x0 - mx), e1 = __expf(x1 - mx);
  float sum = e0 + e1;
  #pragma unroll
  for (int s = 32; s >= 1; s >>= 1) sum += __shfl_xor(sum, s, 64);
  if (ln == 0) reds[wvv] = sum;
  __syncthreads();
  sum = reds[0] + reds[1] + reds[2] + reds[3];
  float rinv = 1.0f / sum;
  float2 o; o.x = e0 * rinv; o.y = e1 * rinv;
  *(float2*)&w_[b * LM_ + m0] = o;
}

// ---------------- k_q: q[b,c] = sum_m P[b,c,m]*w[b,m] ----------------------
__global__ __launch_bounds__(256) void k_q(const float* __restrict__ P,
                                           const float* __restrict__ w,
                                           float* __restrict__ q) {
  int b = blockIdx.y;
  int c0 = blockIdx.x * 32;
  int wvv = threadIdx.x >> 6, ln = threadIdx.x & 63;
  __shared__ float sw[LM_];
  *(float2*)&sw[threadIdx.x * 2] = *(const float2*)&w[b * LM_ + threadIdx.x * 2];
  __syncthreads();
  #pragma unroll
  for (int rr = 0; rr < 8; rr++) {
    int c = c0 + wvv * 8 + rr;
    const float4* Pr = (const float4*)(P + ((size_t)b * LC_ + c) * LM_) + ln * 2;
    float4 p0 = Pr[0], p1 = Pr[1];
    const float4* wr = (const float4*)sw + ln * 2;
    float4 w0 = wr[0], w1 = wr[1];
    float acc = p0.x*w0.x + p0.y*w0.y + p0.z*w0.z + p0.w*w0.w
              + p1.x*w1.x + p1.y*w1.y + p1.z*w1.z + p1.w*w1.w;
    #pragma unroll
    for (int s = 32; s >= 1; s >>= 1) acc += __shfl_xor(acc, s, 64);
    if (ln == 0) q[b * LC_ + c] = acc;
  }
}

// ---------------- k_out: out[b,d] = sum_m w*main - sum_c q*ctx -------------
__global__ __launch_bounds__(256) void k_out(const float* __restrict__ ctx,
                                             const float* __restrict__ mn,
                                             const float* __restrict__ w,
                                             const float* __restrict__ q,
                                             float* __restrict__ out) {
  int b = blockIdx.y;
  int d0 = blockIdx.x * 64;
  int td = threadIdx.x & 63;
  int tg = threadIdx.x >> 6;
  const float* Mb = mn  + (size_t)b * LM_ * D_ + d0;
  const float* Cb = ctx + (size_t)b * LC_ * D_ + d0;
  const float* wb = w + b * LM_;
  const float* qb = q + b * LC_;
  float acc = 0.f;
  #pragma unroll 4
  for (int m = tg; m < LM_; m += 4) acc += wb[m] * Mb[(size_t)m * D_ + td];
  #pragma unroll 4
  for (int c = tg; c < LC_; c += 4) acc -= qb[c] * Cb[(size_t)c * D_ + td];
  __shared__ float red[4][64];
  red[tg][td] = acc;
  __syncthreads();
  if (tg == 0)
    out[b * D_ + d0 + td] = red[0][td] + red[1][td] + red[2][td] + red[3][td];
}

// =====================  LAUNCH  ============================================
extern "C" void kernel_launch(void* const* d_in, const int* in_sizes, int n_in,
                              void* d_out, int out_size, void* d_ws, size_t ws_size,
                              hipStream_t stream) {
  const float* ctx = (const float*)d_in[0];
  const float* mn  = (const float*)d_in[1];
  const float* W   = (const float*)d_in[2];
  float* out = (float*)d_out;

  char* base = (char*)d_ws;
  size_t nPbytes = (size_t)B_ * LC_ * LM_ * 4;       // 134 MB
  size_t planeB  = (size_t)B_ * LM_ * D_ * 2;        // 67 MB per plane

  float* P   = (float*)base;
  short* BtH = (short*)(base + nPbytes);
  short* BtL = (short*)(base + nPbytes + planeB);
  char* p2 = base + nPbytes + 2 * planeB;
  float* tpart = (float*)p2;  p2 += (size_t)B_ * 8 * LM_ * 4;
  float* v = (float*)p2;      p2 += (size_t)B_ * LM_ * 4;
  float* w = (float*)p2;      p2 += (size_t)B_ * LM_ * 4;
  float* q = (float*)p2;

  k_cvt_main<<<dim3(512), 256, 0, stream>>>(mn, W, BtH, BtL, v);
  k_scores_mfma5<<<dim3(1024), 256, 0, stream>>>(ctx, BtH, BtL, W, P, tpart);
  k_tw<<<dim3(B_), 256, 0, stream>>>(tpart, v, w);
  k_q<<<dim3(LC_ / 32, B_), 256, 0, stream>>>(P, w, q);
  k_out<<<dim3(D_ / 64, B_), 256, 0, stream>>>(ctx, mn, w, q, out);
}

// Round 10
// 332.190 us; speedup vs baseline: 1.0378x; 1.0378x over previous
//
#include <hip/hip_runtime.h>

#define B_  128
#define LC_ 512
#define LM_ 512
#define D_  512

typedef __attribute__((ext_vector_type(8))) short short8;
typedef __attribute__((ext_vector_type(16))) float f32x16;
typedef unsigned int u32;

__device__ __forceinline__ unsigned short bf16_rn(float x) {
  unsigned u = __float_as_uint(x);
  unsigned r = u + 0x7fffu + ((u >> 16) & 1u);
  return (unsigned short)(r >> 16);
}

__device__ __forceinline__ void gl_lds16(const void* g, void* l) {
  __builtin_amdgcn_global_load_lds((const __attribute__((address_space(1))) u32*)g,
                                   (__attribute__((address_space(3))) u32*)l, 16, 0, 0);
}

// one fp32 -> (hi,lo) bf16 split + u-dot accumulate; constant IDX only
#define CVT1(SRC, WS, AH, AL, IDX, ACCU)                         \
  { unsigned short hb_ = bf16_rn(SRC);                           \
    float hf_ = __uint_as_float((u32)hb_ << 16);                 \
    AH[IDX] = (short)hb_;                                        \
    AL[IDX] = (short)bf16_rn((SRC) - hf_);                       \
    ACCU = fmaf((SRC), (WS), ACCU); }

// ---------------- k_cvt_main: main fp32 -> tiled fragment-order bf16 planes
// Bt[b][ks][mt][lane][8]; also fused v = main·W. Wave = one (b, mt) tile.
__global__ __launch_bounds__(256) void k_cvt_main(
    const float* __restrict__ mn, const float* __restrict__ W,
    short* __restrict__ BtH, short* __restrict__ BtL,
    float* __restrict__ v) {
  __shared__ float sW[512];
  int tid = threadIdx.x;
  sW[tid] = W[tid];
  sW[tid + 256] = W[tid + 256];
  __syncthreads();
  int wave = blockIdx.x * 4 + (tid >> 6);
  int b = wave >> 4, mt = wave & 15;
  int lane = tid & 63, rowl = lane & 31, h = lane >> 5;
  const float* src = mn + ((size_t)b * LM_ + 32 * mt + rowl) * D_ + 8 * h;
  float acc = 0.f;
  for (int ks = 0; ks < 32; ks++) {
    float4 f0 = *(const float4*)(src + 16 * ks);
    float4 f1 = *(const float4*)(src + 16 * ks + 4);
    int k = 16 * ks + 8 * h;
    float4 w0 = *(const float4*)&sW[k];
    float4 w1 = *(const float4*)&sW[k + 4];
    short8 vh, vl;
    CVT1(f0.x, w0.x, vh, vl, 0, acc); CVT1(f0.y, w0.y, vh, vl, 1, acc);
    CVT1(f0.z, w0.z, vh, vl, 2, acc); CVT1(f0.w, w0.w, vh, vl, 3, acc);
    CVT1(f1.x, w1.x, vh, vl, 4, acc); CVT1(f1.y, w1.y, vh, vl, 5, acc);
    CVT1(f1.z, w1.z, vh, vl, 6, acc); CVT1(f1.w, w1.w, vh, vl, 7, acc);
    size_t off = (((size_t)b * 32 + ks) * 16 + mt) * 512 + (size_t)lane * 8;
    *(short8*)(BtH + off) = vh;
    *(short8*)(BtL + off) = vl;
  }
  acc += __shfl_xor(acc, 32, 64);
  if (h == 0) v[b * LM_ + 32 * mt + rowl] = acc;
}

// ---------------- k_scores_mfma6: 128c x 512m, 8 waves, BK=32, 16 barriers -
// B via gl_lds from tiled planes (double-buffered, 2 ks-slices per buffer);
// A per-wave register cvt (straight-line, slice-by-slice); fused u-dot,
// softmax, t-partials. Numerics identical to R5-R9 (same splits, same order).
struct __align__(16) Smem6 {
  short8 Bf[2][2][2][16][64];  // [buf][sl][pl][mt][lane] 128 KB
  float sW[512];               // 2 KB
  float red[4][128];           // 2 KB
  float cmb[128];
  float uld[128];
  float tpw[2][4][128];        // 4 KB
};

__global__ __launch_bounds__(512, 2) void k_scores_mfma6(
    const float* __restrict__ ctx, const short* __restrict__ BtH,
    const short* __restrict__ BtL, const float* __restrict__ W,
    float* __restrict__ P, float* __restrict__ tpart) {
  __shared__ Smem6 sm;
  int p = blockIdx.x;
  int b = (p & 7) | ((p >> 5) << 3);   // 4 c-blocks of a batch -> same XCD
  int cblk = (p >> 3) & 3;
  int c0 = cblk * 128;
  int tid = threadIdx.x;
  int lane = tid & 63, wv = tid >> 6;
  int rowl = lane & 31, h = lane >> 5;
  int rt0 = (wv >> 2) * 2;             // waves 0-3: rows 0-63; 4-7: 64-127

  f32x16 acc0[4], acc1[4];             // 128 AGPR
  #pragma unroll
  for (int m = 0; m < 4; m++)
    #pragma unroll
    for (int j = 0; j < 16; j++) { acc0[m][j] = 0.f; acc1[m][j] = 0.f; }

  auto stageB = [&](int bf, int ks0) { // stage slices ks0, ks0+1
    #pragma unroll
    for (int sl = 0; sl < 2; sl++)
      #pragma unroll
      for (int rep = 0; rep < 2; rep++) {
        int mt = wv + 8 * rep;
        size_t off = (((size_t)b * 32 + ks0 + sl) * 16 + mt) * 512 + (size_t)lane * 8;
        gl_lds16(BtH + off, &sm.Bf[bf][sl][0][mt][0]);
        gl_lds16(BtL + off, &sm.Bf[bf][sl][1][mt][0]);
      }
  };

  const float* ar0 = ctx + ((size_t)b * LC_ + c0 + 32 * rt0 + rowl) * D_ + 8 * h;
  const float* ar1 = ar0 + 32 * D_;

  sm.sW[tid] = W[tid];
  if (tid < 128) sm.uld[tid] = 0.f;
  stageB(0, 0);
  float accu0 = 0.f, accu1 = 0.f;
  __syncthreads();                     // sW visible + Bf[0] drained

  for (int t = 0; t < 16; t++) {
    int buf = t & 1;
    if (t < 15) stageB(buf ^ 1, 2 * t + 2);

    #pragma unroll
    for (int sl = 0; sl < 2; sl++) {
      int ks = 2 * t + sl;
      int k = 16 * ks + 8 * h;
      float4 w0 = *(const float4*)&sm.sW[k];
      float4 w1 = *(const float4*)&sm.sW[k + 4];
      short8 ah0, al0, ah1, al1;
      {
        const float* p0 = ar0 + 16 * ks;
        float4 g0 = *(const float4*)p0;
        float4 g1 = *(const float4*)(p0 + 4);
        CVT1(g0.x, w0.x, ah0, al0, 0, accu0); CVT1(g0.y, w0.y, ah0, al0, 1, accu0);
        CVT1(g0.z, w0.z, ah0, al0, 2, accu0); CVT1(g0.w, w0.w, ah0, al0, 3, accu0);
        CVT1(g1.x, w1.x, ah0, al0, 4, accu0); CVT1(g1.y, w1.y, ah0, al0, 5, accu0);
        CVT1(g1.z, w1.z, ah0, al0, 6, accu0); CVT1(g1.w, w1.w, ah0, al0, 7, accu0);
      }
      {
        const float* p1 = ar1 + 16 * ks;
        float4 g0 = *(const float4*)p1;
        float4 g1 = *(const float4*)(p1 + 4);
        CVT1(g0.x, w0.x, ah1, al1, 0, accu1); CVT1(g0.y, w0.y, ah1, al1, 1, accu1);
        CVT1(g0.z, w0.z, ah1, al1, 2, accu1); CVT1(g0.w, w0.w, ah1, al1, 3, accu1);
        CVT1(g1.x, w1.x, ah1, al1, 4, accu1); CVT1(g1.y, w1.y, ah1, al1, 5, accu1);
        CVT1(g1.z, w1.z, ah1, al1, 6, accu1); CVT1(g1.w, w1.w, ah1, al1, 7, accu1);
      }
      #pragma unroll
      for (int mtl = 0; mtl < 4; mtl++) {
        int mt = (wv & 3) * 4 + mtl;
        short8 bh = sm.Bf[buf][sl][0][mt][lane];
        short8 bl = sm.Bf[buf][sl][1][mt][lane];
        acc0[mtl] = __builtin_amdgcn_mfma_f32_32x32x16_bf16(ah0, bh, acc0[mtl], 0, 0, 0);
        acc0[mtl] = __builtin_amdgcn_mfma_f32_32x32x16_bf16(ah0, bl, acc0[mtl], 0, 0, 0);
        acc0[mtl] = __builtin_amdgcn_mfma_f32_32x32x16_bf16(al0, bh, acc0[mtl], 0, 0, 0);
        acc1[mtl] = __builtin_amdgcn_mfma_f32_32x32x16_bf16(ah1, bh, acc1[mtl], 0, 0, 0);
        acc1[mtl] = __builtin_amdgcn_mfma_f32_32x32x16_bf16(ah1, bl, acc1[mtl], 0, 0, 0);
        acc1[mtl] = __builtin_amdgcn_mfma_f32_32x32x16_bf16(al1, bh, acc1[mtl], 0, 0, 0);
      }
    }
    __syncthreads();
  }

  // u for this block's 128 c-rows (waves 0 and 4 hold distinct row ranges)
  accu0 += __shfl_xor(accu0, 32, 64);
  accu1 += __shfl_xor(accu1, 32, 64);
  if ((wv & 3) == 0 && h == 0) {
    sm.uld[64 * (wv >> 2) + rowl] = accu0;
    sm.uld[64 * (wv >> 2) + 32 + rowl] = accu1;
  }

  // ---- softmax over m=512 per c-row (cross-wave via LDS) ----
  #pragma unroll
  for (int r = 0; r < 2; r++)
    #pragma unroll
    for (int j = 0; j < 16; j++) {
      float a0 = r ? acc1[0][j] : acc0[0][j];
      float a1 = r ? acc1[1][j] : acc0[1][j];
      float a2 = r ? acc1[2][j] : acc0[2][j];
      float a3 = r ? acc1[3][j] : acc0[3][j];
      float mx = fmaxf(fmaxf(a0, a1), fmaxf(a2, a3));
      #pragma unroll
      for (int s = 1; s <= 16; s <<= 1) mx = fmaxf(mx, __shfl_xor(mx, s, 64));
      if (rowl == 0)
        sm.red[wv & 3][64 * (wv >> 2) + 32 * r + (j & 3) + 8 * (j >> 2) + 4 * h] = mx;
    }
  __syncthreads();
  if (tid < 128)
    sm.cmb[tid] = fmaxf(fmaxf(sm.red[0][tid], sm.red[1][tid]),
                        fmaxf(sm.red[2][tid], sm.red[3][tid]));
  __syncthreads();
  #pragma unroll
  for (int r = 0; r < 2; r++)
    #pragma unroll
    for (int j = 0; j < 16; j++) {
      int row = 64 * (wv >> 2) + 32 * r + (j & 3) + 8 * (j >> 2) + 4 * h;
      float mx = sm.cmb[row];
      float s = 0.f;
      #pragma unroll
      for (int mtl = 0; mtl < 4; mtl++) {
        float e = __expf((r ? acc1[mtl][j] : acc0[mtl][j]) - mx);
        if (r) acc1[mtl][j] = e; else acc0[mtl][j] = e;
        s += e;
      }
      #pragma unroll
      for (int st = 1; st <= 16; st <<= 1) s += __shfl_xor(s, st, 64);
      if (rowl == 0) sm.red[wv & 3][row] = s;
    }
  __syncthreads();
  if (tid < 128)
    sm.cmb[tid] = sm.red[0][tid] + sm.red[1][tid] + sm.red[2][tid] + sm.red[3][tid];
  __syncthreads();

  // ---- P write + fused t-partials (wave owns cols [128(wv&3), +128)) ----
  float* Pb = P + ((size_t)b * LC_ + c0) * LM_;
  float tp[4] = {0.f, 0.f, 0.f, 0.f};
  #pragma unroll
  for (int r = 0; r < 2; r++)
    #pragma unroll
    for (int j = 0; j < 16; j++) {
      int row = 64 * (wv >> 2) + 32 * r + (j & 3) + 8 * (j >> 2) + 4 * h;
      float rinv = 1.f / sm.cmb[row];
      float uu = sm.uld[row];
      #pragma unroll
      for (int mtl = 0; mtl < 4; mtl++) {
        float pv = (r ? acc1[mtl][j] : acc0[mtl][j]) * rinv;
        Pb[(size_t)row * LM_ + 128 * (wv & 3) + 32 * mtl + rowl] = pv;
        tp[mtl] = fmaf(pv, uu, tp[mtl]);
      }
    }
  #pragma unroll
  for (int mtl = 0; mtl < 4; mtl++) tp[mtl] += __shfl_xor(tp[mtl], 32, 64);
  if (h == 0) {
    #pragma unroll
    for (int mtl = 0; mtl < 4; mtl++)
      sm.tpw[wv >> 2][wv & 3][32 * mtl + rowl] = tp[mtl];
  }
  __syncthreads();
  {
    int m = tid;
    tpart[((size_t)b * 4 + cblk) * LM_ + m] =
        sm.tpw[0][m >> 7][m & 127] + sm.tpw[1][m >> 7][m & 127];
  }
}

// ---------------- k_tw: t = v - sum(tpart, 4); w = softmax(t) --------------
__global__ __launch_bounds__(256) void k_tw(const float* __restrict__ tpart,
                                            const float* __restrict__ v,
                                            float* __restrict__ w_) {
  int b = blockIdx.x;
  int tid = threadIdx.x;
  int m0 = tid * 2;
  const float* tp = tpart + (size_t)b * 4 * LM_;
  float s0 = 0.f, s1 = 0.f;
  #pragma unroll
  for (int cb = 0; cb < 4; cb++) {
    s0 += tp[cb * LM_ + m0];
    s1 += tp[cb * LM_ + m0 + 1];
  }
  float x0 = v[b * LM_ + m0] - s0;
  float x1 = v[b * LM_ + m0 + 1] - s1;
  float mx = fmaxf(x0, x1);
  #pragma unroll
  for (int s = 32; s >= 1; s >>= 1) mx = fmaxf(mx, __shfl_xor(mx, s, 64));
  __shared__ float redm[4], reds[4];
  int wvv = tid >> 6, ln = tid & 63;
  if (ln == 0) redm[wvv] = mx;
  __syncthreads();
  mx = fmaxf(fmaxf(redm[0], redm[1]), fmaxf(redm[2], redm[3]));
  float e0 = __expf(x0 - mx), e1 = __expf(x1 - mx);
  float sum = e0 + e1;
  #pragma unroll
  for (int s = 32; s >= 1; s >>= 1) sum += __shfl_xor(sum, s, 64);
  if (ln == 0) reds[wvv] = sum;
  __syncthreads();
  sum = reds[0] + reds[1] + reds[2] + reds[3];
  float rinv = 1.0f / sum;
  float2 o; o.x = e0 * rinv; o.y = e1 * rinv;
  *(float2*)&w_[b * LM_ + m0] = o;
}

// ---------------- k_q: q[b,c] = sum_m P[b,c,m]*w[b,m] ----------------------
__global__ __launch_bounds__(256) void k_q(const float* __restrict__ P,
                                           const float* __restrict__ w,
                                           float* __restrict__ q) {
  int b = blockIdx.y;
  int c0 = blockIdx.x * 32;
  int wvv = threadIdx.x >> 6, ln = threadIdx.x & 63;
  __shared__ float sw[LM_];
  *(float2*)&sw[threadIdx.x * 2] = *(const float2*)&w[b * LM_ + threadIdx.x * 2];
  __syncthreads();
  #pragma unroll
  for (int rr = 0; rr < 8; rr++) {
    int c = c0 + wvv * 8 + rr;
    const float4* Pr = (const float4*)(P + ((size_t)b * LC_ + c) * LM_) + ln * 2;
    float4 p0 = Pr[0], p1 = Pr[1];
    const float4* wr = (const float4*)sw + ln * 2;
    float4 w0 = wr[0], w1 = wr[1];
    float acc = p0.x*w0.x + p0.y*w0.y + p0.z*w0.z + p0.w*w0.w
              + p1.x*w1.x + p1.y*w1.y + p1.z*w1.z + p1.w*w1.w;
    #pragma unroll
    for (int s = 32; s >= 1; s >>= 1) acc += __shfl_xor(acc, s, 64);
    if (ln == 0) q[b * LC_ + c] = acc;
  }
}

// ---------------- k_out: out[b,d] = sum_m w*main - sum_c q*ctx -------------
__global__ __launch_bounds__(256) void k_out(const float* __restrict__ ctx,
                                             const float* __restrict__ mn,
                                             const float* __restrict__ w,
                                             const float* __restrict__ q,
                                             float* __restrict__ out) {
  int b = blockIdx.y;
  int d0 = blockIdx.x * 64;
  int td = threadIdx.x & 63;
  int tg = threadIdx.x >> 6;
  const float* Mb = mn  + (size_t)b * LM_ * D_ + d0;
  const float* Cb = ctx + (size_t)b * LC_ * D_ + d0;
  const float* wb = w + b * LM_;
  const float* qb = q + b * LC_;
  float acc = 0.f;
  #pragma unroll 4
  for (int m = tg; m < LM_; m += 4) acc += wb[m] * Mb[(size_t)m * D_ + td];
  #pragma unroll 4
  for (int c = tg; c < LC_; c += 4) acc -= qb[c] * Cb[(size_t)c * D_ + td];
  __shared__ float red[4][64];
  red[tg][td] = acc;
  __syncthreads();
  if (tg == 0)
    out[b * D_ + d0 + td] = red[0][td] + red[1][td] + red[2][td] + red[3][td];
}

// =====================  LAUNCH  ============================================
extern "C" void kernel_launch(void* const* d_in, const int* in_sizes, int n_in,
                              void* d_out, int out_size, void* d_ws, size_t ws_size,
                              hipStream_t stream) {
  const float* ctx = (const float*)d_in[0];
  const float* mn  = (const float*)d_in[1];
  const float* W   = (const float*)d_in[2];
  float* out = (float*)d_out;

  char* base = (char*)d_ws;
  size_t nPbytes = (size_t)B_ * LC_ * LM_ * 4;       // 134 MB
  size_t planeB  = (size_t)B_ * LM_ * D_ * 2;        // 67 MB per plane

  float* P   = (float*)base;
  short* BtH = (short*)(base + nPbytes);
  short* BtL = (short*)(base + nPbytes + planeB);
  char* p2 = base + nPbytes + 2 * planeB;
  float* tpart = (float*)p2;  p2 += (size_t)B_ * 4 * LM_ * 4;
  float* v = (float*)p2;      p2 += (size_t)B_ * LM_ * 4;
  float* w = (float*)p2;      p2 += (size_t)B_ * LM_ * 4;
  float* q = (float*)p2;

  k_cvt_main<<<dim3(512), 256, 0, stream>>>(mn, W, BtH, BtL, v);
  k_scores_mfma6<<<dim3(512), 512, 0, stream>>>(ctx, BtH, BtL, W, P, tpart);
  k_tw<<<dim3(B_), 256, 0, stream>>>(tpart, v, w);
  k_q<<<dim3(LC_ / 32, B_), 256, 0, stream>>>(P, w, q);
  k_out<<<dim3(D_ / 64, B_), 256, 0, stream>>>(ctx, mn, w, q, out);
}

// Round 13
// 307.352 us; speedup vs baseline: 1.1217x; 1.0808x over previous
//
#include <hip/hip_runtime.h>

#define B_  128
#define LC_ 512
#define LM_ 512
#define D_  512

typedef __attribute__((ext_vector_type(8))) short short8;
typedef __attribute__((ext_vector_type(16))) float f32x16;
typedef unsigned int u32;

__device__ __forceinline__ unsigned short bf16_rn(float x) {
  unsigned u = __float_as_uint(x);
  unsigned r = u + 0x7fffu + ((u >> 16) & 1u);
  return (unsigned short)(r >> 16);
}

// one fp32 -> (hi,lo) bf16 split + u-dot accumulate; constant IDX only
#define CVT1(SRC, WS, AH, AL, IDX, ACCU)                         \
  { unsigned short hb_ = bf16_rn(SRC);                           \
    float hf_ = __uint_as_float((u32)hb_ << 16);                 \
    AH[IDX] = (short)hb_;                                        \
    AL[IDX] = (short)bf16_rn((SRC) - hf_);                       \
    ACCU = fmaf((SRC), (WS), ACCU); }

// ---------------- k_cvt_main: main fp32 -> tiled fragment-order bf16 planes
// Bt[b][ks][mt][lane][8]; also fused v = main·W. Wave = one (b, mt) tile.
__global__ __launch_bounds__(256) void k_cvt_main(
    const float* __restrict__ mn, const float* __restrict__ W,
    short* __restrict__ BtH, short* __restrict__ BtL,
    float* __restrict__ v) {
  __shared__ float sW[512];
  int tid = threadIdx.x;
  sW[tid] = W[tid];
  sW[tid + 256] = W[tid + 256];
  __syncthreads();
  int wave = blockIdx.x * 4 + (tid >> 6);
  int b = wave >> 4, mt = wave & 15;
  int lane = tid & 63, rowl = lane & 31, h = lane >> 5;
  const float* src = mn + ((size_t)b * LM_ + 32 * mt + rowl) * D_ + 8 * h;
  float acc = 0.f;
  for (int ks = 0; ks < 32; ks++) {
    float4 f0 = *(const float4*)(src + 16 * ks);
    float4 f1 = *(const float4*)(src + 16 * ks + 4);
    int k = 16 * ks + 8 * h;
    float4 w0 = *(const float4*)&sW[k];
    float4 w1 = *(const float4*)&sW[k + 4];
    short8 vh, vl;
    CVT1(f0.x, w0.x, vh, vl, 0, acc); CVT1(f0.y, w0.y, vh, vl, 1, acc);
    CVT1(f0.z, w0.z, vh, vl, 2, acc); CVT1(f0.w, w0.w, vh, vl, 3, acc);
    CVT1(f1.x, w1.x, vh, vl, 4, acc); CVT1(f1.y, w1.y, vh, vl, 5, acc);
    CVT1(f1.z, w1.z, vh, vl, 6, acc); CVT1(f1.w, w1.w, vh, vl, 7, acc);
    size_t off = (((size_t)b * 32 + ks) * 16 + mt) * 512 + (size_t)lane * 8;
    *(short8*)(BtH + off) = vh;
    *(short8*)(BtL + off) = vl;
  }
  acc += __shfl_xor(acc, 32, 64);
  if (h == 0) v[b * LM_ + 32 * mt + rowl] = acc;
}

// ---------------- k_scores_mfma7: 128c x 512m, 8 waves, BARRIER-FREE K-loop
// B fragments loaded per-wave DIRECTLY from L2-resident tiled planes into
// registers (1 KB coalesced wave-loads, no LDS staging, no vmcnt(0) drain);
// A per-wave in-register cvt (R10-proven text). Waves fully independent in
// the K-loop; LDS/barriers only for the final softmax/t-partial combine.
struct __align__(16) Smem7 {
  float sW[512];               // 2 KB
  float red[4][128];           // 2 KB
  float cmb[128];
  float uld[128];
  float tpw[2][4][128];        // 4 KB
};

__global__ __launch_bounds__(512, 2) void k_scores_mfma7(
    const float* __restrict__ ctx, const short* __restrict__ BtH,
    const short* __restrict__ BtL, const float* __restrict__ W,
    float* __restrict__ P, float* __restrict__ tpart) {
  __shared__ Smem7 sm;
  int p = blockIdx.x;
  int b = (p & 7) | ((p >> 5) << 3);   // 4 c-blocks of a batch -> same XCD
  int cblk = (p >> 3) & 3;
  int c0 = cblk * 128;
  int tid = threadIdx.x;
  int lane = tid & 63, wv = tid >> 6;
  int rowl = lane & 31, h = lane >> 5;
  int rt0 = (wv >> 2) * 2;             // waves 0-3: rows 0-63; 4-7: 64-127

  f32x16 acc0[4], acc1[4];             // 128 acc regs
  #pragma unroll
  for (int m = 0; m < 4; m++)
    #pragma unroll
    for (int j = 0; j < 16; j++) { acc0[m][j] = 0.f; acc1[m][j] = 0.f; }

  const float* ar0 = ctx + ((size_t)b * LC_ + c0 + 32 * rt0 + rowl) * D_ + 8 * h;
  const float* ar1 = ar0 + 32 * D_;
  // base for this wave's 4 B column-tiles, plane-relative
  size_t boff0 = (((size_t)b * 32) * 16 + (wv & 3) * 4) * 512 + (size_t)lane * 8;

  sm.sW[tid] = W[tid];
  if (tid < 128) sm.uld[tid] = 0.f;
  float accu0 = 0.f, accu1 = 0.f;
  __syncthreads();                     // sW visible

  for (int ks = 0; ks < 32; ks++) {
    // ---- B fragments: direct global->register (L2-hot tiled planes) ----
    short8 bh[4], bl[4];
    size_t bo = boff0 + (size_t)ks * (16 * 512);
    #pragma unroll
    for (int mtl = 0; mtl < 4; mtl++) {
      bh[mtl] = *(const short8*)(BtH + bo + (size_t)mtl * 512);
      bl[mtl] = *(const short8*)(BtL + bo + (size_t)mtl * 512);
    }
    // ---- A: load fp32 + in-register hi/lo cvt (+ u-dot) ----
    int k = 16 * ks + 8 * h;
    float4 w0 = *(const float4*)&sm.sW[k];
    float4 w1 = *(const float4*)&sm.sW[k + 4];
    short8 ah0, al0, ah1, al1;
    {
      const float* p0 = ar0 + 16 * ks;
      float4 g0 = *(const float4*)p0;
      float4 g1 = *(const float4*)(p0 + 4);
      CVT1(g0.x, w0.x, ah0, al0, 0, accu0); CVT1(g0.y, w0.y, ah0, al0, 1, accu0);
      CVT1(g0.z, w0.z, ah0, al0, 2, accu0); CVT1(g0.w, w0.w, ah0, al0, 3, accu0);
      CVT1(g1.x, w1.x, ah0, al0, 4, accu0); CVT1(g1.y, w1.y, ah0, al0, 5, accu0);
      CVT1(g1.z, w1.z, ah0, al0, 6, accu0); CVT1(g1.w, w1.w, ah0, al0, 7, accu0);
    }
    {
      const float* p1 = ar1 + 16 * ks;
      float4 g0 = *(const float4*)p1;
      float4 g1 = *(const float4*)(p1 + 4);
      CVT1(g0.x, w0.x, ah1, al1, 0, accu1); CVT1(g0.y, w0.y, ah1, al1, 1, accu1);
      CVT1(g0.z, w0.z, ah1, al1, 2, accu1); CVT1(g0.w, w0.w, ah1, al1, 3, accu1);
      CVT1(g1.x, w1.x, ah1, al1, 4, accu1); CVT1(g1.y, w1.y, ah1, al1, 5, accu1);
      CVT1(g1.z, w1.z, ah1, al1, 6, accu1); CVT1(g1.w, w1.w, ah1, al1, 7, accu1);
    }
    // ---- MFMA (3-term split, same order as R5-R10) ----
    #pragma unroll
    for (int mtl = 0; mtl < 4; mtl++) {
      acc0[mtl] = __builtin_amdgcn_mfma_f32_32x32x16_bf16(ah0, bh[mtl], acc0[mtl], 0, 0, 0);
      acc0[mtl] = __builtin_amdgcn_mfma_f32_32x32x16_bf16(ah0, bl[mtl], acc0[mtl], 0, 0, 0);
      acc0[mtl] = __builtin_amdgcn_mfma_f32_32x32x16_bf16(al0, bh[mtl], acc0[mtl], 0, 0, 0);
      acc1[mtl] = __builtin_amdgcn_mfma_f32_32x32x16_bf16(ah1, bh[mtl], acc1[mtl], 0, 0, 0);
      acc1[mtl] = __builtin_amdgcn_mfma_f32_32x32x16_bf16(ah1, bl[mtl], acc1[mtl], 0, 0, 0);
      acc1[mtl] = __builtin_amdgcn_mfma_f32_32x32x16_bf16(al1, bh[mtl], acc1[mtl], 0, 0, 0);
    }
  }

  // u for this block's 128 c-rows (waves 0 and 4 hold distinct row ranges)
  accu0 += __shfl_xor(accu0, 32, 64);
  accu1 += __shfl_xor(accu1, 32, 64);
  if ((wv & 3) == 0 && h == 0) {
    sm.uld[64 * (wv >> 2) + rowl] = accu0;
    sm.uld[64 * (wv >> 2) + 32 + rowl] = accu1;
  }

  // ---- softmax over m=512 per c-row (cross-wave via LDS) ----
  #pragma unroll
  for (int r = 0; r < 2; r++)
    #pragma unroll
    for (int j = 0; j < 16; j++) {
      float a0 = r ? acc1[0][j] : acc0[0][j];
      float a1 = r ? acc1[1][j] : acc0[1][j];
      float a2 = r ? acc1[2][j] : acc0[2][j];
      float a3 = r ? acc1[3][j] : acc0[3][j];
      float mx = fmaxf(fmaxf(a0, a1), fmaxf(a2, a3));
      #pragma unroll
      for (int s = 1; s <= 16; s <<= 1) mx = fmaxf(mx, __shfl_xor(mx, s, 64));
      if (rowl == 0)
        sm.red[wv & 3][64 * (wv >> 2) + 32 * r + (j & 3) + 8 * (j >> 2) + 4 * h] = mx;
    }
  __syncthreads();
  if (tid < 128)
    sm.cmb[tid] = fmaxf(fmaxf(sm.red[0][tid], sm.red[1][tid]),
                        fmaxf(sm.red[2][tid], sm.red[3][tid]));
  __syncthreads();
  #pragma unroll
  for (int r = 0; r < 2; r++)
    #pragma unroll
    for (int j = 0; j < 16; j++) {
      int row = 64 * (wv >> 2) + 32 * r + (j & 3) + 8 * (j >> 2) + 4 * h;
      float mx = sm.cmb[row];
      float s = 0.f;
      #pragma unroll
      for (int mtl = 0; mtl < 4; mtl++) {
        float e = __expf((r ? acc1[mtl][j] : acc0[mtl][j]) - mx);
        if (r) acc1[mtl][j] = e; else acc0[mtl][j] = e;
        s += e;
      }
      #pragma unroll
      for (int st = 1; st <= 16; st <<= 1) s += __shfl_xor(s, st, 64);
      if (rowl == 0) sm.red[wv & 3][row] = s;
    }
  __syncthreads();
  if (tid < 128)
    sm.cmb[tid] = sm.red[0][tid] + sm.red[1][tid] + sm.red[2][tid] + sm.red[3][tid];
  __syncthreads();

  // ---- P write + fused t-partials (wave owns cols [128(wv&3), +128)) ----
  float* Pb = P + ((size_t)b * LC_ + c0) * LM_;
  float tp[4] = {0.f, 0.f, 0.f, 0.f};
  #pragma unroll
  for (int r = 0; r < 2; r++)
    #pragma unroll
    for (int j = 0; j < 16; j++) {
      int row = 64 * (wv >> 2) + 32 * r + (j & 3) + 8 * (j >> 2) + 4 * h;
      float rinv = 1.f / sm.cmb[row];
      float uu = sm.uld[row];
      #pragma unroll
      for (int mtl = 0; mtl < 4; mtl++) {
        float pv = (r ? acc1[mtl][j] : acc0[mtl][j]) * rinv;
        Pb[(size_t)row * LM_ + 128 * (wv & 3) + 32 * mtl + rowl] = pv;
        tp[mtl] = fmaf(pv, uu, tp[mtl]);
      }
    }
  #pragma unroll
  for (int mtl = 0; mtl < 4; mtl++) tp[mtl] += __shfl_xor(tp[mtl], 32, 64);
  if (h == 0) {
    #pragma unroll
    for (int mtl = 0; mtl < 4; mtl++)
      sm.tpw[wv >> 2][wv & 3][32 * mtl + rowl] = tp[mtl];
  }
  __syncthreads();
  {
    int m = tid;
    tpart[((size_t)b * 4 + cblk) * LM_ + m] =
        sm.tpw[0][m >> 7][m & 127] + sm.tpw[1][m >> 7][m & 127];
  }
}

// ---------------- k_tw: t = v - sum(tpart, 4); w = softmax(t) --------------
__global__ __launch_bounds__(256) void k_tw(const float* __restrict__ tpart,
                                            const float* __restrict__ v,
                                            float* __restrict__ w_) {
  int b = blockIdx.x;
  int tid = threadIdx.x;
  int m0 = tid * 2;
  const float* tp = tpart + (size_t)b * 4 * LM_;
  float s0 = 0.f, s1 = 0.f;
  #pragma unroll
  for (int cb = 0; cb < 4; cb++) {
    s0 += tp[cb * LM_ + m0];
    s1 += tp[cb * LM_ + m0 + 1];
  }
  float x0 = v[b * LM_ + m0] - s0;
  float x1 = v[b * LM_ + m0 + 1] - s1;
  float mx = fmaxf(x0, x1);
  #pragma unroll
  for (int s = 32; s >= 1; s >>= 1) mx = fmaxf(mx, __shfl_xor(mx, s, 64));
  __shared__ float redm[4], reds[4];
  int wvv = tid >> 6, ln = tid & 63;
  if (ln == 0) redm[wvv] = mx;
  __syncthreads();
  mx = fmaxf(fmaxf(redm[0], redm[1]), fmaxf(redm[2], redm[3]));
  float e0 = __expf(x0 - mx), e1 = __expf(x1 - mx);
  float sum = e0 + e1;
  #pragma unroll
  for (int s = 32; s >= 1; s >>= 1) sum += __shfl_xor(sum, s, 64);
  if (ln == 0) reds[wvv] = sum;
  __syncthreads();
  sum = reds[0] + reds[1] + reds[2] + reds[3];
  float rinv = 1.0f / sum;
  float2 o; o.x = e0 * rinv; o.y = e1 * rinv;
  *(float2*)&w_[b * LM_ + m0] = o;
}

// ---------------- k_q: q[b,c] = sum_m P[b,c,m]*w[b,m] ----------------------
__global__ __launch_bounds__(256) void k_q(const float* __restrict__ P,
                                           const float* __restrict__ w,
                                           float* __restrict__ q) {
  int b = blockIdx.y;
  int c0 = blockIdx.x * 32;
  int wvv = threadIdx.x >> 6, ln = threadIdx.x & 63;
  __shared__ float sw[LM_];
  *(float2*)&sw[threadIdx.x * 2] = *(const float2*)&w[b * LM_ + threadIdx.x * 2];
  __syncthreads();
  #pragma unroll
  for (int rr = 0; rr < 8; rr++) {
    int c = c0 + wvv * 8 + rr;
    const float4* Pr = (const float4*)(P + ((size_t)b * LC_ + c) * LM_) + ln * 2;
    float4 p0 = Pr[0], p1 = Pr[1];
    const float4* wr = (const float4*)sw + ln * 2;
    float4 w0 = wr[0], w1 = wr[1];
    float acc = p0.x*w0.x + p0.y*w0.y + p0.z*w0.z + p0.w*w0.w
              + p1.x*w1.x + p1.y*w1.y + p1.z*w1.z + p1.w*w1.w;
    #pragma unroll
    for (int s = 32; s >= 1; s >>= 1) acc += __shfl_xor(acc, s, 64);
    if (ln == 0) q[b * LC_ + c] = acc;
  }
}

// ---------------- k_out: out[b,d] = sum_m w*main - sum_c q*ctx -------------
__global__ __launch_bounds__(256) void k_out(const float* __restrict__ ctx,
                                             const float* __restrict__ mn,
                                             const float* __restrict__ w,
                                             const float* __restrict__ q,
                                             float* __restrict__ out) {
  int b = blockIdx.y;
  int d0 = blockIdx.x * 64;
  int td = threadIdx.x & 63;
  int tg = threadIdx.x >> 6;
  const float* Mb = mn  + (size_t)b * LM_ * D_ + d0;
  const float* Cb = ctx + (size_t)b * LC_ * D_ + d0;
  const float* wb = w + b * LM_;
  const float* qb = q + b * LC_;
  float acc = 0.f;
  #pragma unroll 4
  for (int m = tg; m < LM_; m += 4) acc += wb[m] * Mb[(size_t)m * D_ + td];
  #pragma unroll 4
  for (int c = tg; c < LC_; c += 4) acc -= qb[c] * Cb[(size_t)c * D_ + td];
  __shared__ float red[4][64];
  red[tg][td] = acc;
  __syncthreads();
  if (tg == 0)
    out[b * D_ + d0 + td] = red[0][td] + red[1][td] + red[2][td] + red[3][td];
}

// =====================  LAUNCH  ============================================
extern "C" void kernel_launch(void* const* d_in, const int* in_sizes, int n_in,
                              void* d_out, int out_size, void* d_ws, size_t ws_size,
                              hipStream_t stream) {
  const float* ctx = (const float*)d_in[0];
  const float* mn  = (const float*)d_in[1];
  const float* W   = (const float*)d_in[2];
  float* out = (float*)d_out;

  char* base = (char*)d_ws;
  size_t nPbytes = (size_t)B_ * LC_ * LM_ * 4;       // 134 MB
  size_t planeB  = (size_t)B_ * LM_ * D_ * 2;        // 67 MB per plane

  float* P   = (float*)base;
  short* BtH = (short*)(base + nPbytes);
  short* BtL = (short*)(base + nPbytes + planeB);
  char* p2 = base + nPbytes + 2 * planeB;
  float* tpart = (float*)p2;  p2 += (size_t)B_ * 4 * LM_ * 4;
  float* v = (float*)p2;      p2 += (size_t)B_ * LM_ * 4;
  float* w = (float*)p2;      p2 += (size_t)B_ * LM_ * 4;
  float* q = (float*)p2;

  k_cvt_main<<<dim3(512), 256, 0, stream>>>(mn, W, BtH, BtL, v);
  k_scores_mfma7<<<dim3(512), 512, 0, stream>>>(ctx, BtH, BtL, W, P, tpart);
  k_tw<<<dim3(B_), 256, 0, stream>>>(tpart, v, w);
  k_q<<<dim3(LC_ / 32, B_), 256, 0, stream>>>(P, w, q);
  k_out<<<dim3(D_ / 64, B_), 256, 0, stream>>>(ctx, mn, w, q, out);
}